// Round 1
// baseline (879.837 us; speedup 1.0000x reference)
//
#include <hip/hip_runtime.h>
#include <math.h>

#define NPTS 4096
#define LOGN 8.317766166719343f   // log(4096)
#define LN2f 0.6931471805599453f
#define LOG2E 1.4426950408889634f

// ws layout (floats):
// [0, 16384)          : px  (float4[4096] = x,y,z,|p|^2)
// [16384, 32768)      : py  (float4[4096])
// [32768, 32768+24576): duals: fxy, gxy, fxx, gxx, fyy, gyy (each 4096)

__global__ void prep_kernel(const float* __restrict__ x, const float* __restrict__ y,
                            float* __restrict__ ws) {
    int j = blockIdx.x * blockDim.x + threadIdx.x;
    if (j < NPTS) {
        float4* px = (float4*)ws;
        float4* py = (float4*)(ws + 4 * NPTS);
        float ax = x[3*j], ay = x[3*j+1], az = x[3*j+2];
        px[j] = make_float4(ax, ay, az, ax*ax + ay*ay + az*az);
        float bx = y[3*j], by = y[3*j+1], bz = y[3*j+2];
        py[j] = make_float4(bx, by, bz, bx*bx + by*by + bz*bz);
        float* duals = ws + 8 * NPTS;
        #pragma unroll
        for (int p = 0; p < 6; ++p) duals[p * NPTS + j] = 0.0f;
    }
}

// One Sinkhorn half-update for all 3 OT problems.
// half==0: f_i = -eps*(lb + LSE_j((g_j - C_ij)/eps))   (rows are the f-side points)
// half==1: g_j = -eps*(la + LSE_i((f_i - C_ij)/eps))   (rows are the g-side points)
__launch_bounds__(256)
__global__ void sinkhorn_half(const float* __restrict__ ws_ro, float* __restrict__ duals,
                              float eps, int half) {
    const float4* px = (const float4*)ws_ro;
    const float4* py = (const float4*)(ws_ro + 4 * NPTS);

    int prob = blockIdx.x >> 8;      // 0: xy, 1: xx, 2: yy
    int blk  = blockIdx.x & 255;     // 256 blocks per problem, 16 rows each

    const float4* rows; const float4* cols;
    const float* gin; float* fout;
    if (half == 0) {
        rows = (prob == 2) ? py : px;           // xy: x, xx: x, yy: y
        cols = (prob == 1) ? px : py;           // xy: y, xx: x, yy: y
        gin  = duals + prob * 2 * NPTS + NPTS;  // read g
        fout = duals + prob * 2 * NPTS;         // write f
    } else {
        rows = (prob == 1) ? px : py;           // xy: y, xx: x, yy: y
        cols = (prob == 2) ? py : px;           // xy: x, xx: x, yy: y
        gin  = duals + prob * 2 * NPTS;         // read f
        fout = duals + prob * 2 * NPTS + NPTS;  // write g
    }

    int wave = threadIdx.x >> 6;
    int lane = threadIdx.x & 63;
    int r0 = blk * 16 + wave * 4;

    const float k = LOG2E / eps;     // log2(e)/eps : work in base-2 logs
    const float nhk = -0.5f * k;

    float axk[4], ayk[4], azk[4], rak[4], m[4], s[4];
    #pragma unroll
    for (int r = 0; r < 4; ++r) {
        float4 a = rows[r0 + r];
        axk[r] = a.x * k; ayk[r] = a.y * k; azk[r] = a.z * k;
        rak[r] = nhk * a.w;
        m[r] = -INFINITY; s[r] = 0.0f;
    }

    for (int j = lane; j < NPTS; j += 64) {
        float4 b = cols[j];
        float u = fmaf(b.w, nhk, gin[j] * k);   // k*(g_j - 0.5*|b|^2)
        #pragma unroll
        for (int r = 0; r < 4; ++r) {
            // t = k*(g_j - C_rj), C = 0.5(|a|^2+|b|^2) - a.b
            float t = fmaf(axk[r], b.x, fmaf(ayk[r], b.y, fmaf(azk[r], b.z, u + rak[r])));
            float mn = fmaxf(m[r], t);
            s[r] = fmaf(s[r], exp2f(m[r] - mn), exp2f(t - mn));
            m[r] = mn;
        }
    }

    // butterfly LSE-merge across the 64-lane wave
    #pragma unroll
    for (int r = 0; r < 4; ++r) {
        float mm = m[r], ss = s[r];
        for (int off = 32; off > 0; off >>= 1) {
            float m2 = __shfl_xor(mm, off);
            float s2 = __shfl_xor(ss, off);
            float mn = fmaxf(mm, m2);
            ss = fmaf(ss, exp2f(mm - mn), s2 * exp2f(m2 - mn));
            mm = mn;
        }
        if (lane == 0) {
            float lse2 = mm + log2f(ss);                   // log2(sum exp)
            fout[r0 + r] = -eps * fmaf(LN2f, lse2, -LOGN); // -eps*(lb + ln-LSE)
        }
    }
}

__global__ void finalize_kernel(const float* __restrict__ duals, float* __restrict__ out) {
    int tid = threadIdx.x;
    double acc = 0.0;
    for (int i = tid; i < 2 * NPTS; i += 256) acc += (double)duals[i];            // fxy+gxy
    double acc2 = 0.0;
    for (int i = tid; i < 4 * NPTS; i += 256) acc2 += (double)duals[2*NPTS + i];  // xx+yy duals
    acc -= 0.5 * acc2;
    for (int off = 32; off > 0; off >>= 1) acc += __shfl_xor(acc, off);
    __shared__ double red[4];
    int wave = tid >> 6, lane = tid & 63;
    if (lane == 0) red[wave] = acc;
    __syncthreads();
    if (tid == 0) {
        double tot = red[0] + red[1] + red[2] + red[3];
        out[0] = (float)(tot / (double)NPTS);
    }
}

extern "C" void kernel_launch(void* const* d_in, const int* in_sizes, int n_in,
                              void* d_out, int out_size, void* d_ws, size_t ws_size,
                              hipStream_t stream) {
    const float* x = (const float*)d_in[0];
    const float* y = (const float*)d_in[1];
    float* ws = (float*)d_ws;
    float* out = (float*)d_out;
    float* duals = ws + 8 * NPTS;

    prep_kernel<<<dim3((NPTS + 255) / 256), dim3(256), 0, stream>>>(x, y, ws);

    // static epsilon schedule, matching the reference exactly
    float eps_list[16]; int n = 0;
    double e = 4.0;
    while (e > 0.0025) { eps_list[n++] = (float)e; e *= 0.25; }
    for (int i = 0; i < 5; ++i) eps_list[n++] = 0.0025f;

    for (int st = 0; st < n; ++st) {
        sinkhorn_half<<<dim3(768), dim3(256), 0, stream>>>(ws, duals, eps_list[st], 0);
        sinkhorn_half<<<dim3(768), dim3(256), 0, stream>>>(ws, duals, eps_list[st], 1);
    }

    finalize_kernel<<<dim3(1), dim3(256), 0, stream>>>(duals, out);
}

// Round 2
// 616.760 us; speedup vs baseline: 1.4265x; 1.4265x over previous
//
#include <hip/hip_runtime.h>
#include <math.h>

#define NPTS 4096
#define LOGN 8.317766166719343f   // log(4096)
#define LN2f 0.6931471805599453f
#define LOG2E 1.4426950408889634f

// ws layout (floats):
// [0, 16384)          : px  (float4[4096] = x,y,z,|p|^2)
// [16384, 32768)      : py  (float4[4096])
// [32768, 32768+24576): duals: fxy, gxy, fxx, gxx, fyy, gyy (each 4096)

__global__ void prep_kernel(const float* __restrict__ x, const float* __restrict__ y,
                            float* __restrict__ ws) {
    int j = blockIdx.x * blockDim.x + threadIdx.x;
    if (j < NPTS) {
        float4* px = (float4*)ws;
        float4* py = (float4*)(ws + 4 * NPTS);
        float ax = x[3*j], ay = x[3*j+1], az = x[3*j+2];
        px[j] = make_float4(ax, ay, az, ax*ax + ay*ay + az*az);
        float bx = y[3*j], by = y[3*j+1], bz = y[3*j+2];
        py[j] = make_float4(bx, by, bz, bx*bx + by*by + bz*bz);
        float* duals = ws + 8 * NPTS;
        #pragma unroll
        for (int p = 0; p < 6; ++p) duals[p * NPTS + j] = 0.0f;
    }
}

// One Sinkhorn half-update for all 3 OT problems.
// half==0: f_i = -eps*(lb + LSE_j((g_j - C_ij)/eps))
// half==1: g_j = -eps*(la + LSE_i((f_i - C_ij)/eps))
__launch_bounds__(256)
__global__ void sinkhorn_half(const float* __restrict__ ws_ro, float* __restrict__ duals,
                              float eps, int half) {
    const float4* px = (const float4*)ws_ro;
    const float4* py = (const float4*)(ws_ro + 4 * NPTS);

    int prob = blockIdx.x >> 8;      // 0: xy, 1: xx, 2: yy
    int blk  = blockIdx.x & 255;     // 256 blocks per problem, 16 rows each

    const float4* rows; const float4* cols;
    const float* gin; float* fout;
    if (half == 0) {
        rows = (prob == 2) ? py : px;           // xy: x, xx: x, yy: y
        cols = (prob == 1) ? px : py;           // xy: y, xx: x, yy: y
        gin  = duals + prob * 2 * NPTS + NPTS;  // read g
        fout = duals + prob * 2 * NPTS;         // write f
    } else {
        rows = (prob == 1) ? px : py;           // xy: y, xx: x, yy: y
        cols = (prob == 2) ? py : px;           // xy: x, xx: x, yy: y
        gin  = duals + prob * 2 * NPTS;         // read f
        fout = duals + prob * 2 * NPTS + NPTS;  // write g
    }

    const float k = LOG2E / eps;     // log2(e)/eps : work in base-2 logs
    const float nhk = -0.5f * k;

    // Stage u[j] = k*(g_j - 0.5*|b_j|^2) in LDS once per block (shared by all rows).
    __shared__ float u_lds[NPTS];
    {
        int tid = threadIdx.x;
        #pragma unroll
        for (int i = 0; i < NPTS / 256; ++i) {
            int j = i * 256 + tid;
            float4 b = cols[j];
            u_lds[j] = fmaf(b.w, nhk, gin[j] * k);
        }
    }
    __syncthreads();

    int wave = threadIdx.x >> 6;
    int lane = threadIdx.x & 63;
    int r0 = blk * 16 + wave * 4;

    float axk[4], ayk[4], azk[4], rak[4], m[4], s[4];
    #pragma unroll
    for (int r = 0; r < 4; ++r) {
        float4 a = rows[r0 + r];
        axk[r] = a.x * k; ayk[r] = a.y * k; azk[r] = a.z * k;
        rak[r] = nhk * a.w;               // k*(-0.5*|a|^2), folded in at epilogue
        m[r] = -INFINITY; s[r] = 0.0f;
    }

    for (int j = lane; j < NPTS; j += 64) {
        float4 b = cols[j];
        float u = u_lds[j];
        #pragma unroll
        for (int r = 0; r < 4; ++r) {
            // t' = k*(g_j - C_rj) - rak = dot3(ak, b) + u
            float t = fmaf(axk[r], b.x, fmaf(ayk[r], b.y, fmaf(azk[r], b.z, u)));
            float mn = fmaxf(m[r], t);
            s[r] = fmaf(s[r], __builtin_amdgcn_exp2f(m[r] - mn),
                        __builtin_amdgcn_exp2f(t - mn));
            m[r] = mn;
        }
    }

    // butterfly LSE-merge across the 64-lane wave
    #pragma unroll
    for (int r = 0; r < 4; ++r) {
        float mm = m[r], ss = s[r];
        for (int off = 32; off > 0; off >>= 1) {
            float m2 = __shfl_xor(mm, off);
            float s2 = __shfl_xor(ss, off);
            float mn = fmaxf(mm, m2);
            ss = fmaf(ss, __builtin_amdgcn_exp2f(mm - mn),
                      s2 * __builtin_amdgcn_exp2f(m2 - mn));
            mm = mn;
        }
        if (lane == 0) {
            // full log2-LSE = rak + mm + log2(ss)
            float lse2 = rak[r] + mm + __builtin_amdgcn_logf(ss);
            fout[r0 + r] = -eps * fmaf(LN2f, lse2, -LOGN); // -eps*(lb + ln-LSE)
        }
    }
}

__global__ void finalize_kernel(const float* __restrict__ duals, float* __restrict__ out) {
    int tid = threadIdx.x;
    double acc = 0.0;
    for (int i = tid; i < 2 * NPTS; i += 256) acc += (double)duals[i];            // fxy+gxy
    double acc2 = 0.0;
    for (int i = tid; i < 4 * NPTS; i += 256) acc2 += (double)duals[2*NPTS + i];  // xx+yy duals
    acc -= 0.5 * acc2;
    for (int off = 32; off > 0; off >>= 1) acc += __shfl_xor(acc, off);
    __shared__ double red[4];
    int wave = tid >> 6, lane = tid & 63;
    if (lane == 0) red[wave] = acc;
    __syncthreads();
    if (tid == 0) {
        double tot = red[0] + red[1] + red[2] + red[3];
        out[0] = (float)(tot / (double)NPTS);
    }
}

extern "C" void kernel_launch(void* const* d_in, const int* in_sizes, int n_in,
                              void* d_out, int out_size, void* d_ws, size_t ws_size,
                              hipStream_t stream) {
    const float* x = (const float*)d_in[0];
    const float* y = (const float*)d_in[1];
    float* ws = (float*)d_ws;
    float* out = (float*)d_out;
    float* duals = ws + 8 * NPTS;

    prep_kernel<<<dim3((NPTS + 255) / 256), dim3(256), 0, stream>>>(x, y, ws);

    // static epsilon schedule, matching the reference exactly
    float eps_list[16]; int n = 0;
    double e = 4.0;
    while (e > 0.0025) { eps_list[n++] = (float)e; e *= 0.25; }
    for (int i = 0; i < 5; ++i) eps_list[n++] = 0.0025f;

    for (int st = 0; st < n; ++st) {
        sinkhorn_half<<<dim3(768), dim3(256), 0, stream>>>(ws, duals, eps_list[st], 0);
        sinkhorn_half<<<dim3(768), dim3(256), 0, stream>>>(ws, duals, eps_list[st], 1);
    }

    finalize_kernel<<<dim3(1), dim3(256), 0, stream>>>(duals, out);
}

// Round 3
// 611.733 us; speedup vs baseline: 1.4383x; 1.0082x over previous
//
#include <hip/hip_runtime.h>
#include <math.h>

#define NPTS 4096
#define LOGN 8.317766166719343f   // log(4096)
#define LN2f 0.6931471805599453f
#define LOG2E 1.4426950408889634f

#define JSPLIT 4
#define JCHUNK (NPTS / JSPLIT)            // 1024 columns per wave
#define RPW 8                             // rows per wave
#define RPB 32                            // rows per block (4 waves)
#define NRBLK (NPTS / RPB)                // 128
#define BLOCKS_PER_PROB (NRBLK * JSPLIT)  // 512

// ws float layout:
// [0,16384)            px (float4[4096] = x,y,z,|p|^2)
// [16384,32768)        py
// [32768,131072)       m_part : [(prob*2+side)*JSPLIT + p][row]   (side 0=f,1=g)
// [131072,229376)      s_part : same layout
#define PX_OFF 0
#define PY_OFF (4 * NPTS)
#define MPART_OFF (8 * NPTS)
#define SPART_OFF (MPART_OFF + 6 * JSPLIT * NPTS)

__global__ void prep_kernel(const float* __restrict__ x, const float* __restrict__ y,
                            float* __restrict__ ws) {
    int j = blockIdx.x * 256 + threadIdx.x;
    if (j >= NPTS) return;
    float4* px = (float4*)(ws + PX_OFF);
    float4* py = (float4*)(ws + PY_OFF);
    float ax = x[3*j], ay = x[3*j+1], az = x[3*j+2];
    px[j] = make_float4(ax, ay, az, ax*ax + ay*ay + az*az);
    float bx = y[3*j], by = y[3*j+1], bz = y[3*j+2];
    py[j] = make_float4(bx, by, bz, bx*bx + by*by + bz*bz);
    // init partials so that decoded dual == 0 at any eps:
    // lse2 = 12 (=log2 4096) -> -eps*(lb + ln2*12) = -eps*(-logN + logN) = 0
    float* mp = ws + MPART_OFF;
    float* sp = ws + SPART_OFF;
    #pragma unroll
    for (int ps = 0; ps < 6; ++ps) {
        #pragma unroll
        for (int p = 0; p < JSPLIT; ++p) {
            int idx = (ps * JSPLIT + p) * NPTS + j;
            mp[idx] = (p == 0) ? 12.0f : 0.0f;
            sp[idx] = (p == 0) ? 1.0f : 0.0f;
        }
    }
}

// One Sinkhorn half-update for all 3 OT problems, 4-way j-split.
// Duals are stored as per-jsplit LSE partials (m,s); the merge of the INPUT
// side's partials is fused into the LDS staging phase.
__launch_bounds__(256, 6)
__global__ void sinkhorn_half(float* __restrict__ ws, float eps, float eps_dec, int half) {
    const float4* px = (const float4*)(ws + PX_OFF);
    const float4* py = (const float4*)(ws + PY_OFF);
    const float* mp = ws + MPART_OFF;
    const float* sp = ws + SPART_OFF;

    int bid = blockIdx.x;
    int prob = bid / BLOCKS_PER_PROB;       // 0: xy, 1: xx, 2: yy
    int rem = bid % BLOCKS_PER_PROB;
    int js = rem & (JSPLIT - 1);
    int rblk = rem / JSPLIT;

    const float4* rows; const float4* cols;
    int in_side, out_side;
    if (half == 0) {  // f-update: rows = f-side points, cols = g-side points
        rows = (prob == 2) ? py : px;
        cols = (prob == 1) ? px : py;
        in_side = 1; out_side = 0;
    } else {          // g-update
        rows = (prob == 1) ? px : py;
        cols = (prob == 2) ? py : px;
        in_side = 0; out_side = 1;
    }

    const float k = LOG2E / eps;     // base-2 log scale
    const float nhk = -0.5f * k;
    const int jbase = js * JCHUNK;

    // Stage u[j] = k*(g_j - 0.5*|b_j|^2) for this block's j-chunk.
    // g_j is decoded by merging the input side's 4 partials (written at eps_dec).
    __shared__ float u_lds[JCHUNK];
    {
        int in_base = (prob * 2 + in_side) * JSPLIT * NPTS;
        for (int i = threadIdx.x; i < JCHUNK; i += 256) {
            int j = jbase + i;
            float m0 = mp[in_base + 0*NPTS + j], m1 = mp[in_base + 1*NPTS + j];
            float m2 = mp[in_base + 2*NPTS + j], m3 = mp[in_base + 3*NPTS + j];
            float M = fmaxf(fmaxf(m0, m1), fmaxf(m2, m3));
            float ssum = sp[in_base + 0*NPTS + j] * __builtin_amdgcn_exp2f(m0 - M)
                       + sp[in_base + 1*NPTS + j] * __builtin_amdgcn_exp2f(m1 - M)
                       + sp[in_base + 2*NPTS + j] * __builtin_amdgcn_exp2f(m2 - M)
                       + sp[in_base + 3*NPTS + j] * __builtin_amdgcn_exp2f(m3 - M);
            float lse2 = M + __builtin_amdgcn_logf(ssum);
            float g = -eps_dec * fmaf(LN2f, lse2, -LOGN);
            float4 b = cols[j];
            u_lds[i] = fmaf(b.w, nhk, g * k);
        }
    }
    __syncthreads();

    int wave = threadIdx.x >> 6;
    int lane = threadIdx.x & 63;
    int r0 = rblk * RPB + wave * RPW;

    float axk[RPW], ayk[RPW], azk[RPW], rak[RPW], m[RPW], s[RPW];
    #pragma unroll
    for (int r = 0; r < RPW; ++r) {
        float4 a = rows[r0 + r];
        axk[r] = a.x * k; ayk[r] = a.y * k; azk[r] = a.z * k;
        rak[r] = nhk * a.w;           // k*(-0.5*|a|^2), folded in at partial-write
        m[r] = -INFINITY; s[r] = 0.0f;
    }

    for (int it = 0; it < JCHUNK / 64; ++it) {
        int jo = it * 64 + lane;
        float4 b = cols[jbase + jo];
        float u = u_lds[jo];
        #pragma unroll
        for (int r = 0; r < RPW; ++r) {
            float t = fmaf(axk[r], b.x, fmaf(ayk[r], b.y, fmaf(azk[r], b.z, u)));
            float mn = fmaxf(m[r], t);
            s[r] = fmaf(s[r], __builtin_amdgcn_exp2f(m[r] - mn),
                        __builtin_amdgcn_exp2f(t - mn));
            m[r] = mn;
        }
    }

    // wave reduce: max butterfly, one rescale, sum butterfly; write partial
    int out_base = ((prob * 2 + out_side) * JSPLIT + js) * NPTS + r0;
    #pragma unroll
    for (int r = 0; r < RPW; ++r) {
        float M = m[r];
        for (int off = 32; off; off >>= 1) M = fmaxf(M, __shfl_xor(M, off));
        float ss = s[r] * __builtin_amdgcn_exp2f(m[r] - M);
        for (int off = 32; off; off >>= 1) ss += __shfl_xor(ss, off);
        if (lane == 0) {
            ws[MPART_OFF + out_base + r] = M + rak[r];
            ws[SPART_OFF + out_base + r] = ss;
        }
    }
}

__global__ void finalize_kernel(const float* __restrict__ ws, float* __restrict__ out,
                                float eps) {
    const float* mp = ws + MPART_OFF;
    const float* sp = ws + SPART_OFF;
    int tid = threadIdx.x;
    double acc = 0.0;
    for (int idx = tid; idx < 6 * NPTS; idx += 256) {
        int ps = idx >> 12;            // prob*2+side
        int row = idx & (NPTS - 1);
        int base = ps * JSPLIT * NPTS + row;
        float m0 = mp[base], m1 = mp[base + NPTS], m2 = mp[base + 2*NPTS], m3 = mp[base + 3*NPTS];
        float M = fmaxf(fmaxf(m0, m1), fmaxf(m2, m3));
        float ssum = sp[base]          * __builtin_amdgcn_exp2f(m0 - M)
                   + sp[base + NPTS]   * __builtin_amdgcn_exp2f(m1 - M)
                   + sp[base + 2*NPTS] * __builtin_amdgcn_exp2f(m2 - M)
                   + sp[base + 3*NPTS] * __builtin_amdgcn_exp2f(m3 - M);
        float lse2 = M + __builtin_amdgcn_logf(ssum);
        float dual = -eps * fmaf(LN2f, lse2, -LOGN);
        acc += ((ps < 2) ? 1.0 : -0.5) * (double)dual;
    }
    for (int off = 32; off; off >>= 1) acc += __shfl_xor(acc, off);
    __shared__ double red[4];
    int wave = tid >> 6, lane = tid & 63;
    if (lane == 0) red[wave] = acc;
    __syncthreads();
    if (tid == 0) out[0] = (float)((red[0] + red[1] + red[2] + red[3]) / (double)NPTS);
}

extern "C" void kernel_launch(void* const* d_in, const int* in_sizes, int n_in,
                              void* d_out, int out_size, void* d_ws, size_t ws_size,
                              hipStream_t stream) {
    const float* x = (const float*)d_in[0];
    const float* y = (const float*)d_in[1];
    float* ws = (float*)d_ws;
    float* out = (float*)d_out;

    prep_kernel<<<dim3((NPTS + 255) / 256), dim3(256), 0, stream>>>(x, y, ws);

    // static epsilon schedule, matching the reference exactly
    float eps_list[16]; int n = 0;
    double e = 4.0;
    while (e > 0.0025) { eps_list[n++] = (float)e; e *= 0.25; }
    for (int i = 0; i < 5; ++i) eps_list[n++] = 0.0025f;

    for (int st = 0; st < n; ++st) {
        float ep = eps_list[st];
        float ed0 = (st == 0) ? eps_list[0] : eps_list[st - 1]; // decode eps for g-partials
        sinkhorn_half<<<dim3(3 * BLOCKS_PER_PROB), dim3(256), 0, stream>>>(ws, ep, ed0, 0);
        sinkhorn_half<<<dim3(3 * BLOCKS_PER_PROB), dim3(256), 0, stream>>>(ws, ep, ep, 1);
    }

    finalize_kernel<<<dim3(1), dim3(256), 0, stream>>>(ws, out, eps_list[n - 1]);
}

// Round 4
// 418.928 us; speedup vs baseline: 2.1002x; 1.4602x over previous
//
#include <hip/hip_runtime.h>
#include <math.h>

#define NPTS 4096
#define LOGN 8.317766166719343f   // log(4096)
#define LN2f 0.6931471805599453f
#define LOG2E 1.4426950408889634f

#define JSPLIT 2
#define JCHUNK (NPTS / JSPLIT)            // 2048 columns per block
#define RPW 8                             // rows per wave
#define RPB 32                            // rows per block (4 waves)
#define NRBLK (NPTS / RPB)                // 128
#define BPP (NRBLK * JSPLIT)              // 256 blocks per problem; grid = 768

typedef float f2 __attribute__((ext_vector_type(2)));
static __device__ __forceinline__ f2 mk2(float a, float b) { f2 r; r.x = a; r.y = b; return r; }

// ws float layout:
// SoA points: PT(cloud, coord): cloud 0=x,1=y; coord 0=x,1=y,2=z,3=|p|^2  -> [0, 32768)
// m_part @ MPART_OFF: [(prob*2+side)*JSPLIT + p][row]   (side 0=f, 1=g)
// s_part @ SPART_OFF: same layout
#define PT(cloud, coord) ((cloud) * 4 * NPTS + (coord) * NPTS)
#define MPART_OFF (8 * NPTS)
#define SPART_OFF (MPART_OFF + 6 * JSPLIT * NPTS)

__global__ void prep_kernel(const float* __restrict__ x, const float* __restrict__ y,
                            float* __restrict__ ws) {
    int j = blockIdx.x * 256 + threadIdx.x;
    if (j >= NPTS) return;
    float ax = x[3*j], ay = x[3*j+1], az = x[3*j+2];
    ws[PT(0,0)+j] = ax; ws[PT(0,1)+j] = ay; ws[PT(0,2)+j] = az;
    ws[PT(0,3)+j] = ax*ax + ay*ay + az*az;
    float bx = y[3*j], by = y[3*j+1], bz = y[3*j+2];
    ws[PT(1,0)+j] = bx; ws[PT(1,1)+j] = by; ws[PT(1,2)+j] = bz;
    ws[PT(1,3)+j] = bx*bx + by*by + bz*bz;
    // init partials so decoded dual == 0 at any eps: lse2 = 12 = log2(4096)
    float* mp = ws + MPART_OFF;
    float* sp = ws + SPART_OFF;
    #pragma unroll
    for (int ps = 0; ps < 6; ++ps) {
        mp[(ps*JSPLIT+0)*NPTS + j] = 12.0f; sp[(ps*JSPLIT+0)*NPTS + j] = 1.0f;
        mp[(ps*JSPLIT+1)*NPTS + j] = 0.0f;  sp[(ps*JSPLIT+1)*NPTS + j] = 0.0f;
    }
}

// One Sinkhorn half-update for all 3 OT problems, 2-way j-split, chunked-max LSE.
__launch_bounds__(256, 3)
__global__ void sinkhorn_half(float* __restrict__ ws, float eps, float eps_dec, int half) {
    int bid = blockIdx.x;
    int prob = bid / BPP;                 // 0: xy, 1: xx, 2: yy
    int rem  = bid % BPP;
    int js   = rem & (JSPLIT - 1);
    int rblk = rem / JSPLIT;

    int rc, cc, in_side, out_side;
    if (half == 0) { rc = (prob == 2) ? 1 : 0; cc = (prob == 1) ? 0 : 1; in_side = 1; out_side = 0; }
    else           { rc = (prob == 1) ? 0 : 1; cc = (prob == 2) ? 1 : 0; in_side = 0; out_side = 1; }

    const float k = LOG2E / eps;          // base-2 log scale
    const float nhk = -0.5f * k;
    const int jbase = js * JCHUNK;

    __shared__ float bxL[JCHUNK], byL[JCHUNK], bzL[JCHUNK], uL[JCHUNK];

    // ---- stage SoA cols + decode input duals into u = k*(g_j - 0.5*|b_j|^2) ----
    {
        const float* cx = ws + PT(cc, 0);
        const float* cy = ws + PT(cc, 1);
        const float* cz = ws + PT(cc, 2);
        const float* cw = ws + PT(cc, 3);
        const float* mp = ws + MPART_OFF + (prob*2 + in_side) * JSPLIT * NPTS;
        const float* sp = ws + SPART_OFF + (prob*2 + in_side) * JSPLIT * NPTS;
        for (int i = threadIdx.x; i < JCHUNK; i += 256) {
            int j = jbase + i;
            float m0 = mp[j], m1 = mp[NPTS + j];
            float s0 = sp[j], s1 = sp[NPTS + j];
            float M = fmaxf(m0, m1);
            float ssum = fmaf(s0, __builtin_amdgcn_exp2f(m0 - M),
                              s1 * __builtin_amdgcn_exp2f(m1 - M));
            float lse2 = M + __builtin_amdgcn_logf(ssum);
            float g = -eps_dec * fmaf(LN2f, lse2, -LOGN);
            bxL[i] = cx[j]; byL[i] = cy[j]; bzL[i] = cz[j];
            uL[i] = fmaf(cw[j], nhk, g * k);
        }
    }
    __syncthreads();

    int wave = threadIdx.x >> 6;
    int lane = threadIdx.x & 63;
    int r0 = rblk * RPB + wave * RPW;

    const float* rx = ws + PT(rc, 0);
    const float* ry = ws + PT(rc, 1);
    const float* rz = ws + PT(rc, 2);
    const float* rw = ws + PT(rc, 3);

    f2 AX[RPW], AY[RPW], AZ[RPW];
    float rak[RPW], m[RPW], s[RPW];
    #pragma unroll
    for (int r = 0; r < RPW; ++r) {
        float ax = rx[r0+r] * k, ay = ry[r0+r] * k, az = rz[r0+r] * k;
        AX[r] = mk2(ax, ax); AY[r] = mk2(ay, ay); AZ[r] = mk2(az, az);
        rak[r] = nhk * rw[r0+r];
        m[r] = -INFINITY; s[r] = 0.0f;
    }

    // ---- main loop: 8 j's per lane per superiter, chunk-local max, 1 rescale ----
    for (int su = 0; su < JCHUNK / 512; ++su) {     // 4 superiters
        int c0 = su * 512 + lane;
        f2 BX[4], BY[4], BZ[4], U[4];
        #pragma unroll
        for (int p = 0; p < 4; ++p) {
            int j0 = c0 + p * 128;
            BX[p] = mk2(bxL[j0], bxL[j0 + 64]);
            BY[p] = mk2(byL[j0], byL[j0 + 64]);
            BZ[p] = mk2(bzL[j0], bzL[j0 + 64]);
            U[p]  = mk2(uL[j0],  uL[j0 + 64]);
        }
        #pragma unroll
        for (int r = 0; r < RPW; ++r) {
            f2 t0 = __builtin_elementwise_fma(AX[r], BX[0],
                     __builtin_elementwise_fma(AY[r], BY[0],
                      __builtin_elementwise_fma(AZ[r], BZ[0], U[0])));
            f2 t1 = __builtin_elementwise_fma(AX[r], BX[1],
                     __builtin_elementwise_fma(AY[r], BY[1],
                      __builtin_elementwise_fma(AZ[r], BZ[1], U[1])));
            f2 t2 = __builtin_elementwise_fma(AX[r], BX[2],
                     __builtin_elementwise_fma(AY[r], BY[2],
                      __builtin_elementwise_fma(AZ[r], BZ[2], U[2])));
            f2 t3 = __builtin_elementwise_fma(AX[r], BX[3],
                     __builtin_elementwise_fma(AY[r], BY[3],
                      __builtin_elementwise_fma(AZ[r], BZ[3], U[3])));
            f2 q = __builtin_elementwise_max(
                     __builtin_elementwise_max(t0, t1),
                     __builtin_elementwise_max(t2, t3));
            float mn = fmaxf(fmaxf(q.x, q.y), m[r]);       // v_max3
            float er = __builtin_amdgcn_exp2f(m[r] - mn);  // chunk rescale (1/8 per elem)
            f2 mn2 = mk2(mn, mn);
            f2 d0 = t0 - mn2, d1 = t1 - mn2, d2 = t2 - mn2, d3 = t3 - mn2;
            f2 e0, e1, e2, e3;
            e0.x = __builtin_amdgcn_exp2f(d0.x); e0.y = __builtin_amdgcn_exp2f(d0.y);
            e1.x = __builtin_amdgcn_exp2f(d1.x); e1.y = __builtin_amdgcn_exp2f(d1.y);
            e2.x = __builtin_amdgcn_exp2f(d2.x); e2.y = __builtin_amdgcn_exp2f(d2.y);
            e3.x = __builtin_amdgcn_exp2f(d3.x); e3.y = __builtin_amdgcn_exp2f(d3.y);
            f2 acc = (e0 + e1) + (e2 + e3);
            s[r] = fmaf(s[r], er, acc.x + acc.y);
            m[r] = mn;
        }
    }

    // ---- wave reduce: max butterfly, one rescale, sum butterfly; write partial ----
    int out_base = ((prob*2 + out_side) * JSPLIT + js) * NPTS + r0;
    #pragma unroll
    for (int r = 0; r < RPW; ++r) {
        float M = m[r];
        for (int off = 32; off; off >>= 1) M = fmaxf(M, __shfl_xor(M, off));
        float ss = s[r] * __builtin_amdgcn_exp2f(m[r] - M);
        for (int off = 32; off; off >>= 1) ss += __shfl_xor(ss, off);
        if (lane == 0) {
            ws[MPART_OFF + out_base + r] = M + rak[r];
            ws[SPART_OFF + out_base + r] = ss;
        }
    }
}

__global__ void finalize_kernel(const float* __restrict__ ws, float* __restrict__ out,
                                float eps) {
    const float* mp = ws + MPART_OFF;
    const float* sp = ws + SPART_OFF;
    int tid = threadIdx.x;
    double acc = 0.0;
    for (int idx = tid; idx < 6 * NPTS; idx += 256) {
        int ps = idx >> 12;            // prob*2+side
        int row = idx & (NPTS - 1);
        int base = ps * JSPLIT * NPTS + row;
        float m0 = mp[base], m1 = mp[base + NPTS];
        float s0 = sp[base], s1 = sp[base + NPTS];
        float M = fmaxf(m0, m1);
        float ssum = fmaf(s0, __builtin_amdgcn_exp2f(m0 - M),
                          s1 * __builtin_amdgcn_exp2f(m1 - M));
        float lse2 = M + __builtin_amdgcn_logf(ssum);
        float dual = -eps * fmaf(LN2f, lse2, -LOGN);
        acc += ((ps < 2) ? 1.0 : -0.5) * (double)dual;
    }
    for (int off = 32; off; off >>= 1) acc += __shfl_xor(acc, off);
    __shared__ double red[4];
    int wave = tid >> 6, lane = tid & 63;
    if (lane == 0) red[wave] = acc;
    __syncthreads();
    if (tid == 0) out[0] = (float)((red[0] + red[1] + red[2] + red[3]) / (double)NPTS);
}

extern "C" void kernel_launch(void* const* d_in, const int* in_sizes, int n_in,
                              void* d_out, int out_size, void* d_ws, size_t ws_size,
                              hipStream_t stream) {
    const float* x = (const float*)d_in[0];
    const float* y = (const float*)d_in[1];
    float* ws = (float*)d_ws;
    float* out = (float*)d_out;

    prep_kernel<<<dim3((NPTS + 255) / 256), dim3(256), 0, stream>>>(x, y, ws);

    // static epsilon schedule, matching the reference exactly
    float eps_list[16]; int n = 0;
    double e = 4.0;
    while (e > 0.0025) { eps_list[n++] = (float)e; e *= 0.25; }
    for (int i = 0; i < 5; ++i) eps_list[n++] = 0.0025f;

    for (int st = 0; st < n; ++st) {
        float ep = eps_list[st];
        float ed0 = (st == 0) ? eps_list[0] : eps_list[st - 1]; // decode eps for g-partials
        sinkhorn_half<<<dim3(3 * BPP), dim3(256), 0, stream>>>(ws, ep, ed0, 0);
        sinkhorn_half<<<dim3(3 * BPP), dim3(256), 0, stream>>>(ws, ep, ep, 1);
    }

    finalize_kernel<<<dim3(1), dim3(256), 0, stream>>>(ws, out, eps_list[n - 1]);
}